// Round 1
// baseline (428.838 us; speedup 1.0000x reference)
//
#include <hip/hip_runtime.h>
#include <hip/hip_bf16.h>

typedef __attribute__((ext_vector_type(4))) float f32x4;
typedef __attribute__((ext_vector_type(8))) short bf16x8;

#define AS1 __attribute__((address_space(1)))
#define AS3 __attribute__((address_space(3)))

__device__ __forceinline__ void gload16(const void* g, void* l) {
    __builtin_amdgcn_global_load_lds((AS1 const void*)g, (AS3 void*)l, 16, 0, 0);
}

__device__ __forceinline__ unsigned short f2bf(float f) {
    union { float f; unsigned int u; } v; v.f = f;
    unsigned int u = v.u;
    unsigned int r = (u + 0x7FFFu + ((u >> 16) & 1u)) >> 16;
    return (unsigned short)r;
}

__device__ __forceinline__ float gelu_t(float x) {
    float u = 0.7978845608028654f * (x + 0.044715f * x * x * x);
    return 0.5f * x * (1.0f + tanhf(u));
}

// ---------------------------------------------------------------------------
// Generic bf16 GEMM: C(MxN) = A(MxK) @ Bt(NxK)^T  [+ epilogue]
// EPI 0: store bf16
// EPI 1: v + bias[col] + res[row*N+col] -> store f32
// EPI 2: gelu(v + bias[col]) -> store bf16
// 128x128 tile, BK=32, 256 threads (4 waves, 2x2), m97 2-barrier structure.
// ---------------------------------------------------------------------------
template<int EPI>
__global__ __launch_bounds__(256) void gemm_bt(
    const unsigned short* __restrict__ A,
    const unsigned short* __restrict__ Bt,
    void* __restrict__ C,
    const float* __restrict__ bias,
    const float* __restrict__ res,
    int M, int N, int K)
{
    __shared__ alignas(16) unsigned short As[128 * 32];
    __shared__ alignas(16) unsigned short Bs[128 * 32];
    const int t = threadIdx.x;
    const int lane = t & 63;
    const int w = t >> 6;
    const int la = lane & 15, lg = lane >> 4;
    const int brow = blockIdx.x * 128, bcol = blockIdx.y * 128;
    const int wr = (w >> 1) * 64, wc = (w & 1) * 64;

    // staging: thread t loads 16B; rows t/4 (+64), k-offset (t%4)*8
    const int srow = t >> 2;
    const int scol = (t & 3) * 8;
    const unsigned short* aS0 = A + (size_t)(brow + srow) * K + scol;
    const unsigned short* aS1 = A + (size_t)(brow + 64 + srow) * K + scol;
    const unsigned short* bS0 = Bt + (size_t)(bcol + srow) * K + scol;
    const unsigned short* bS1 = Bt + (size_t)(bcol + 64 + srow) * K + scol;
    unsigned short* aD = As + t * 8;
    unsigned short* bD = Bs + t * 8;

    f32x4 acc[4][4];
#pragma unroll
    for (int m = 0; m < 4; m++)
#pragma unroll
        for (int n = 0; n < 4; n++)
            acc[m][n] = (f32x4){0.f, 0.f, 0.f, 0.f};

    for (int k0 = 0; k0 < K; k0 += 32) {
        __syncthreads();   // previous tile's reads done
        gload16(aS0 + k0, aD);
        gload16(aS1 + k0, aD + 2048);
        gload16(bS0 + k0, bD);
        gload16(bS1 + k0, bD + 2048);
        __syncthreads();   // staged data landed (syncthreads drains vmcnt)

        bf16x8 af[4], bfv[4];
#pragma unroll
        for (int m = 0; m < 4; m++)
            af[m] = *(const bf16x8*)(As + (wr + m * 16 + la) * 32 + lg * 8);
#pragma unroll
        for (int n = 0; n < 4; n++)
            bfv[n] = *(const bf16x8*)(Bs + (wc + n * 16 + la) * 32 + lg * 8);
#pragma unroll
        for (int m = 0; m < 4; m++)
#pragma unroll
            for (int n = 0; n < 4; n++)
                acc[m][n] = __builtin_amdgcn_mfma_f32_16x16x32_bf16(
                    af[m], bfv[n], acc[m][n], 0, 0, 0);
    }

    // epilogue: C/D layout col = lane&15, row = (lane>>4)*4 + j  (m89-verified)
#pragma unroll
    for (int m = 0; m < 4; m++)
#pragma unroll
        for (int n = 0; n < 4; n++)
#pragma unroll
            for (int j = 0; j < 4; j++) {
                int row = brow + wr + m * 16 + lg * 4 + j;
                int col = bcol + wc + n * 16 + la;
                float v = acc[m][n][j];
                if (EPI == 0) {
                    ((unsigned short*)C)[(size_t)row * N + col] = f2bf(v);
                } else if (EPI == 1) {
                    ((float*)C)[(size_t)row * N + col] =
                        v + bias[col] + res[(size_t)row * N + col];
                } else {
                    ((unsigned short*)C)[(size_t)row * N + col] =
                        f2bf(gelu_t(v + bias[col]));
                }
            }
}

// ---------------------------------------------------------------------------
// Causal flash attention. QKV: [4096][3072] bf16 (Q|K|V), Vt: [b][h][64][2048]
// Block: 64 q rows (4 waves x 16), KV tiles of 64. Output ctx [4096][1024] bf16
// ---------------------------------------------------------------------------
__global__ __launch_bounds__(256) void attn_kernel(
    const unsigned short* __restrict__ QKV,
    const unsigned short* __restrict__ Vt,
    unsigned short* __restrict__ ctx)
{
    __shared__ alignas(16) unsigned short Ks[64 * 64];
    __shared__ alignas(16) unsigned short Vs[64 * 64];
    __shared__ alignas(16) unsigned short Ps[4][16 * 64];
    const int t = threadIdx.x, lane = t & 63, w = t >> 6;
    const int la = lane & 15, lg = lane >> 4;
    const int qt = blockIdx.x, h = blockIdx.y, b = blockIdx.z;
    const int qbase = qt * 64;

    // Q fragments (A layout: row = lane&15, k = (lane>>4)*8 + e), held in regs
    const unsigned short* qp =
        QKV + (size_t)(b * 2048 + qbase + w * 16 + la) * 3072 + h * 64;
    bf16x8 qf0 = *(const bf16x8*)(qp + lg * 8);
    bf16x8 qf1 = *(const bf16x8*)(qp + 32 + lg * 8);

    f32x4 o[4];
#pragma unroll
    for (int n = 0; n < 4; n++) o[n] = (f32x4){0.f, 0.f, 0.f, 0.f};
    float mrow[4] = {-1e30f, -1e30f, -1e30f, -1e30f};
    float lrow[4] = {0.f, 0.f, 0.f, 0.f};

    const unsigned short* kg = QKV + (size_t)(b * 2048) * 3072 + 1024 + h * 64;
    const unsigned short* vg = Vt + (size_t)((b * 16 + h) * 64) * 2048;
    const int srow = t >> 3;          // 0..31
    const int scol = (t & 7) * 8;     // 0..56

    const int nt = qbase / 64 + 1;
    for (int kt = 0; kt < nt; ++kt) {
        const int kv = kt * 64;
        __syncthreads();
        // K tile -> Ks[key][hd] (64x64), V tile -> Vs[hd][key]
        gload16(kg + (size_t)(kv + srow) * 3072 + scol, Ks + t * 8);
        gload16(kg + (size_t)(kv + 32 + srow) * 3072 + scol, Ks + 2048 + t * 8);
        gload16(vg + (size_t)srow * 2048 + kv + scol, Vs + t * 8);
        gload16(vg + (size_t)(32 + srow) * 2048 + kv + scol, Vs + 2048 + t * 8);
        __syncthreads();

        // scores: S[16q][64k] = Q @ K^T
        f32x4 sa[4];
#pragma unroll
        for (int n = 0; n < 4; n++) {
            f32x4 z = (f32x4){0.f, 0.f, 0.f, 0.f};
            bf16x8 k0 = *(const bf16x8*)(Ks + (n * 16 + la) * 64 + lg * 8);
            bf16x8 k1 = *(const bf16x8*)(Ks + (n * 16 + la) * 64 + 32 + lg * 8);
            z = __builtin_amdgcn_mfma_f32_16x16x32_bf16(qf0, k0, z, 0, 0, 0);
            z = __builtin_amdgcn_mfma_f32_16x16x32_bf16(qf1, k1, z, 0, 0, 0);
            sa[n] = z;
        }
        const bool diag = (kt == nt - 1);
#pragma unroll
        for (int n = 0; n < 4; n++)
#pragma unroll
            for (int j = 0; j < 4; j++) {
                float s = sa[n][j] * 0.125f;  // 1/sqrt(64)
                if (diag) {
                    int qr = qbase + w * 16 + lg * 4 + j;
                    int kc = kv + n * 16 + la;
                    if (kc > qr) s = -1e30f;
                }
                sa[n][j] = s;
            }
        // row max over 64 keys (4 local + 16-lane reduce)
        float pm[4];
#pragma unroll
        for (int j = 0; j < 4; j++)
            pm[j] = fmaxf(fmaxf(sa[0][j], sa[1][j]), fmaxf(sa[2][j], sa[3][j]));
#pragma unroll
        for (int off = 1; off < 16; off <<= 1)
#pragma unroll
            for (int j = 0; j < 4; j++)
                pm[j] = fmaxf(pm[j], __shfl_xor(pm[j], off, 64));
        float alpha[4];
#pragma unroll
        for (int j = 0; j < 4; j++) {
            float mn = fmaxf(mrow[j], pm[j]);
            alpha[j] = exp2f((mrow[j] - mn) * 1.44269504f);
            mrow[j] = mn;
        }
        float psum[4] = {0.f, 0.f, 0.f, 0.f};
#pragma unroll
        for (int n = 0; n < 4; n++)
#pragma unroll
            for (int j = 0; j < 4; j++) {
                float p = exp2f((sa[n][j] - mrow[j]) * 1.44269504f);
                sa[n][j] = p;
                psum[j] += p;
            }
#pragma unroll
        for (int off = 1; off < 16; off <<= 1)
#pragma unroll
            for (int j = 0; j < 4; j++)
                psum[j] += __shfl_xor(psum[j], off, 64);
#pragma unroll
        for (int j = 0; j < 4; j++) {
            lrow[j] = lrow[j] * alpha[j] + psum[j];
            o[0][j] *= alpha[j]; o[1][j] *= alpha[j];
            o[2][j] *= alpha[j]; o[3][j] *= alpha[j];
        }
        // P (C-layout) -> per-wave LDS scratch -> A-layout fragments
        unsigned short* pw = (unsigned short*)Ps[w];
#pragma unroll
        for (int n = 0; n < 4; n++)
#pragma unroll
            for (int j = 0; j < 4; j++)
                pw[(lg * 4 + j) * 64 + n * 16 + la] = f2bf(sa[n][j]);
        asm volatile("s_waitcnt lgkmcnt(0)" ::: "memory");
#pragma unroll
        for (int kk = 0; kk < 2; kk++) {
            bf16x8 pa = *(const bf16x8*)(pw + la * 64 + kk * 32 + lg * 8);
#pragma unroll
            for (int n = 0; n < 4; n++) {
                bf16x8 vb = *(const bf16x8*)(Vs + (n * 16 + la) * 64 + kk * 32 + lg * 8);
                o[n] = __builtin_amdgcn_mfma_f32_16x16x32_bf16(pa, vb, o[n], 0, 0, 0);
            }
        }
    }
    float inv[4];
#pragma unroll
    for (int j = 0; j < 4; j++) inv[j] = 1.0f / lrow[j];
#pragma unroll
    for (int n = 0; n < 4; n++)
#pragma unroll
        for (int j = 0; j < 4; j++) {
            int row = b * 2048 + qbase + w * 16 + lg * 4 + j;
            int col = h * 64 + n * 16 + la;
            ctx[(size_t)row * 1024 + col] = f2bf(o[n][j] * inv[j]);
        }
}

// ---------------------------------------------------------------------------
// LayerNorm (unbiased var, ddof=1), D=1024, one block per row, f32 -> bf16
// ---------------------------------------------------------------------------
__global__ __launch_bounds__(256) void ln_kernel(
    const float* __restrict__ x, const float* __restrict__ scale,
    const float* __restrict__ shift, unsigned short* __restrict__ out)
{
    const int row = blockIdx.x, t = threadIdx.x;
    const int lane = t & 63, w = t >> 6;
    const float4 v = ((const float4*)(x + (size_t)row * 1024))[t];
    float s = v.x + v.y + v.z + v.w;
#pragma unroll
    for (int off = 1; off < 64; off <<= 1) s += __shfl_xor(s, off, 64);
    __shared__ float red[8];
    if (lane == 0) red[w] = s;
    __syncthreads();
    float mean = (red[0] + red[1] + red[2] + red[3]) * (1.0f / 1024.0f);
    float d0 = v.x - mean, d1 = v.y - mean, d2 = v.z - mean, d3 = v.w - mean;
    float q = d0 * d0 + d1 * d1 + d2 * d2 + d3 * d3;
#pragma unroll
    for (int off = 1; off < 64; off <<= 1) q += __shfl_xor(q, off, 64);
    if (lane == 0) red[4 + w] = q;
    __syncthreads();
    float var = (red[4] + red[5] + red[6] + red[7]) * (1.0f / 1023.0f);
    float rinv = rsqrtf(var + 1e-6f);
    const int c = t * 4;
    out[(size_t)row * 1024 + c + 0] = f2bf(scale[c + 0] * (d0 * rinv) + shift[c + 0]);
    out[(size_t)row * 1024 + c + 1] = f2bf(scale[c + 1] * (d1 * rinv) + shift[c + 1]);
    out[(size_t)row * 1024 + c + 2] = f2bf(scale[c + 2] * (d2 * rinv) + shift[c + 2]);
    out[(size_t)row * 1024 + c + 3] = f2bf(scale[c + 3] * (d3 * rinv) + shift[c + 3]);
}

// ---------------------------------------------------------------------------
// Weight transpose: W[K][N] f32 -> Wt[N][K] bf16. block(32,8), grid(N/32,K/32)
// ---------------------------------------------------------------------------
__global__ __launch_bounds__(256) void transpose_w(
    const float* __restrict__ W, unsigned short* __restrict__ Wt, int K, int N)
{
    __shared__ float tile[32][33];
    const int nb = blockIdx.x * 32, kb = blockIdx.y * 32;
    const int tx = threadIdx.x, ty = threadIdx.y;
#pragma unroll
    for (int j = 0; j < 4; j++)
        tile[ty + j * 8][tx] = W[(size_t)(kb + ty + j * 8) * N + nb + tx];
    __syncthreads();
#pragma unroll
    for (int j = 0; j < 4; j++)
        Wt[(size_t)(nb + ty + j * 8) * K + kb + tx] = f2bf(tile[tx][ty + j * 8]);
}

// ---------------------------------------------------------------------------
// V transpose: QKV V-section [s][h*64+hd] -> Vt[b][h][hd][s]
// block(32,8), grid(S/32, 2, B*H)
// ---------------------------------------------------------------------------
__global__ __launch_bounds__(256) void transpose_v(
    const unsigned short* __restrict__ QKV, unsigned short* __restrict__ Vt)
{
    __shared__ unsigned short tile[32][33];
    const int sb = blockIdx.x * 32, hb = blockIdx.y * 32;
    const int bh = blockIdx.z;
    const int b = bh >> 4, h = bh & 15;
    const int tx = threadIdx.x, ty = threadIdx.y;
    const unsigned short* src = QKV + (size_t)(b * 2048) * 3072 + 2048 + h * 64;
#pragma unroll
    for (int j = 0; j < 4; j++)
        tile[ty + j * 8][tx] = src[(size_t)(sb + ty + j * 8) * 3072 + hb + tx];
    __syncthreads();
    unsigned short* dst = Vt + (size_t)((b * 16 + h) * 64) * 2048;
#pragma unroll
    for (int j = 0; j < 4; j++)
        dst[(size_t)(hb + ty + j * 8) * 2048 + sb + tx] = tile[tx][ty + j * 8];
}

// ---------------------------------------------------------------------------
extern "C" void kernel_launch(void* const* d_in, const int* in_sizes, int n_in,
                              void* d_out, int out_size, void* d_ws, size_t ws_size,
                              hipStream_t stream)
{
    const float* x      = (const float*)d_in[0];
    const float* Wq     = (const float*)d_in[1];
    const float* Wk     = (const float*)d_in[2];
    const float* Wv     = (const float*)d_in[3];
    const float* Wo     = (const float*)d_in[4];
    const float* bo     = (const float*)d_in[5];
    const float* W1     = (const float*)d_in[6];
    const float* b1     = (const float*)d_in[7];
    const float* W2     = (const float*)d_in[8];
    const float* b2     = (const float*)d_in[9];
    const float* scale1 = (const float*)d_in[10];
    const float* shift1 = (const float*)d_in[11];
    const float* scale2 = (const float*)d_in[12];
    const float* shift2 = (const float*)d_in[13];
    float* out = (float*)d_out;

    char* ws = (char*)d_ws;
    unsigned short* xn    = (unsigned short*)(ws);                   // 8MB (also yn)
    unsigned short* QKV   = (unsigned short*)(ws + (8ull << 20));    // 24MB
    unsigned short* VtB   = (unsigned short*)(ws + (32ull << 20));   // 8MB
    unsigned short* ctx   = (unsigned short*)(ws + (40ull << 20));   // 8MB
    unsigned short* g     = (unsigned short*)(ws + (8ull << 20));    // 32MB (reuse QKV+Vt)
    unsigned short* WqkvT = (unsigned short*)(ws + (48ull << 20));   // 6MB
    unsigned short* WoT   = (unsigned short*)(ws + (54ull << 20));   // 2MB
    unsigned short* W1T   = (unsigned short*)(ws + (56ull << 20));   // 8MB
    unsigned short* W2T   = (unsigned short*)(ws + (64ull << 20));   // 8MB -> 72MB total
    float* h = out;  // h lives in d_out (FFN2 reads h[idx] then writes out[idx])

    dim3 blk(256);
    dim3 tb(32, 8);

    // weight transposes (f32 -> bf16, K x N -> N x K)
    transpose_w<<<dim3(32, 32), tb, 0, stream>>>(Wq, WqkvT, 1024, 1024);
    transpose_w<<<dim3(32, 32), tb, 0, stream>>>(Wk, WqkvT + 1024 * 1024, 1024, 1024);
    transpose_w<<<dim3(32, 32), tb, 0, stream>>>(Wv, WqkvT + 2 * 1024 * 1024, 1024, 1024);
    transpose_w<<<dim3(32, 32), tb, 0, stream>>>(Wo, WoT, 1024, 1024);
    transpose_w<<<dim3(128, 32), tb, 0, stream>>>(W1, W1T, 1024, 4096);
    transpose_w<<<dim3(32, 128), tb, 0, stream>>>(W2, W2T, 4096, 1024);

    // LN1: xn = LN(x)
    ln_kernel<<<4096, blk, 0, stream>>>(x, scale1, shift1, xn);
    // QKV = xn @ [Wq|Wk|Wv]
    gemm_bt<0><<<dim3(32, 24), blk, 0, stream>>>(xn, WqkvT, QKV, nullptr, nullptr,
                                                 4096, 3072, 1024);
    // Vt
    transpose_v<<<dim3(64, 2, 32), tb, 0, stream>>>(QKV, VtB);
    // attention -> ctx
    attn_kernel<<<dim3(32, 16, 2), blk, 0, stream>>>(QKV, VtB, ctx);
    // h = x + ctx @ Wo + bo   (h in d_out)
    gemm_bt<1><<<dim3(32, 8), blk, 0, stream>>>(ctx, WoT, h, bo, x, 4096, 1024, 1024);
    // LN2: yn = LN(h)  (reuse xn buffer)
    ln_kernel<<<4096, blk, 0, stream>>>(h, scale2, shift2, xn);
    // g = gelu(yn @ W1 + b1)
    gemm_bt<2><<<dim3(32, 32), blk, 0, stream>>>(xn, W1T, g, b1, nullptr, 4096, 4096, 1024);
    // out = h + g @ W2 + b2
    gemm_bt<1><<<dim3(32, 8), blk, 0, stream>>>(g, W2T, out, b2, h, 4096, 1024, 4096);
}

// Round 2
// 342.547 us; speedup vs baseline: 1.2519x; 1.2519x over previous
//
#include <hip/hip_runtime.h>
#include <hip/hip_bf16.h>

typedef __attribute__((ext_vector_type(4))) float f32x4;
typedef __attribute__((ext_vector_type(8))) short bf16x8;

#define AS1 __attribute__((address_space(1)))
#define AS3 __attribute__((address_space(3)))

__device__ __forceinline__ void gload16(const void* g, void* l) {
    __builtin_amdgcn_global_load_lds((AS1 const void*)g, (AS3 void*)l, 16, 0, 0);
}

__device__ __forceinline__ unsigned short f2bf(float f) {
    union { float f; unsigned int u; } v; v.f = f;
    unsigned int u = v.u;
    unsigned int r = (u + 0x7FFFu + ((u >> 16) & 1u)) >> 16;
    return (unsigned short)r;
}

__device__ __forceinline__ float gelu_t(float x) {
    float u = 0.7978845608028654f * (x + 0.044715f * x * x * x);
    return 0.5f * x * (1.0f + tanhf(u));
}

// ---------------------------------------------------------------------------
// Generic bf16 GEMM: C(MxN) = A(MxK) @ Bt(NxK)^T  [+ epilogue]
// EPI 0: store bf16
// EPI 1: v + bias[col] + res[row*N+col] -> store f32
// EPI 2: gelu(v + bias[col]) -> store bf16
// 128x128 tile, BK=32, 256 threads (4 waves, 2x2), m97 2-barrier structure.
// ---------------------------------------------------------------------------
template<int EPI>
__global__ __launch_bounds__(256) void gemm_bt(
    const unsigned short* __restrict__ A,
    const unsigned short* __restrict__ Bt,
    void* __restrict__ C,
    const float* __restrict__ bias,
    const float* __restrict__ res,
    int M, int N, int K)
{
    __shared__ alignas(16) unsigned short As[128 * 32];
    __shared__ alignas(16) unsigned short Bs[128 * 32];
    const int t = threadIdx.x;
    const int lane = t & 63;
    const int w = t >> 6;
    const int la = lane & 15, lg = lane >> 4;
    const int brow = blockIdx.x * 128, bcol = blockIdx.y * 128;
    const int wr = (w >> 1) * 64, wc = (w & 1) * 64;

    const int srow = t >> 2;
    const int scol = (t & 3) * 8;
    const unsigned short* aS0 = A + (size_t)(brow + srow) * K + scol;
    const unsigned short* aS1 = A + (size_t)(brow + 64 + srow) * K + scol;
    const unsigned short* bS0 = Bt + (size_t)(bcol + srow) * K + scol;
    const unsigned short* bS1 = Bt + (size_t)(bcol + 64 + srow) * K + scol;
    unsigned short* aD = As + t * 8;
    unsigned short* bD = Bs + t * 8;

    f32x4 acc[4][4];
#pragma unroll
    for (int m = 0; m < 4; m++)
#pragma unroll
        for (int n = 0; n < 4; n++)
            acc[m][n] = (f32x4){0.f, 0.f, 0.f, 0.f};

    for (int k0 = 0; k0 < K; k0 += 32) {
        __syncthreads();
        gload16(aS0 + k0, aD);
        gload16(aS1 + k0, aD + 2048);
        gload16(bS0 + k0, bD);
        gload16(bS1 + k0, bD + 2048);
        __syncthreads();

        bf16x8 af[4], bfv[4];
#pragma unroll
        for (int m = 0; m < 4; m++)
            af[m] = *(const bf16x8*)(As + (wr + m * 16 + la) * 32 + lg * 8);
#pragma unroll
        for (int n = 0; n < 4; n++)
            bfv[n] = *(const bf16x8*)(Bs + (wc + n * 16 + la) * 32 + lg * 8);
#pragma unroll
        for (int m = 0; m < 4; m++)
#pragma unroll
            for (int n = 0; n < 4; n++)
                acc[m][n] = __builtin_amdgcn_mfma_f32_16x16x32_bf16(
                    af[m], bfv[n], acc[m][n], 0, 0, 0);
    }

#pragma unroll
    for (int m = 0; m < 4; m++)
#pragma unroll
        for (int n = 0; n < 4; n++)
#pragma unroll
            for (int j = 0; j < 4; j++) {
                int row = brow + wr + m * 16 + lg * 4 + j;
                int col = bcol + wc + n * 16 + la;
                float v = acc[m][n][j];
                if (EPI == 0) {
                    ((unsigned short*)C)[(size_t)row * N + col] = f2bf(v);
                } else if (EPI == 1) {
                    ((float*)C)[(size_t)row * N + col] =
                        v + bias[col] + res[(size_t)row * N + col];
                } else {
                    ((unsigned short*)C)[(size_t)row * N + col] =
                        f2bf(gelu_t(v + bias[col]));
                }
            }
}

// ---------------------------------------------------------------------------
// Causal flash attention, swizzled LDS + work-balanced pairing.
// QKV: [4096][3072] bf16 (Q|K|V), Vt: [b][h][64][2048]
// Block p handles q-tiles p and 31-p serially -> 33 KV-tile iters per block.
// LDS tiles 64x64 bf16 (8 chunks of 16B per 128B row), XOR-swizzled:
// data chunk c of row r lives at chunk c ^ (r&7). Staging keeps the LDS dest
// LINEAR (global_load_lds requirement) and inverse-swizzles the global source
// column; all ds_reads apply the same XOR.
// ---------------------------------------------------------------------------
__global__ __launch_bounds__(256) void attn_kernel(
    const unsigned short* __restrict__ QKV,
    const unsigned short* __restrict__ Vt,
    unsigned short* __restrict__ ctx)
{
    __shared__ alignas(16) unsigned short Ks[64 * 64];
    __shared__ alignas(16) unsigned short Vs[64 * 64];
    __shared__ alignas(16) unsigned short Ps[4][16 * 64];
    const int t = threadIdx.x, lane = t & 63, w = t >> 6;
    const int la = lane & 15, lg = lane >> 4;
    const int p = blockIdx.x, h = blockIdx.y, b = blockIdx.z;

    const unsigned short* kg = QKV + (size_t)(b * 2048) * 3072 + 1024 + h * 64;
    const unsigned short* vg = Vt + (size_t)((b * 16 + h) * 64) * 2048;
    const int srow = t >> 3;                       // 0..31
    const int sxcol = (((t & 7) ^ (srow & 7)) * 8); // inverse-swizzled source col

    unsigned short* pw = (unsigned short*)Ps[w];
    const int xk = la & 7;  // row-XOR key for all fragment reads (row%8 == la%8)

    for (int half = 0; half < 2; ++half) {
        const int qt = half ? (31 - p) : p;
        const int qbase = qt * 64;

        const unsigned short* qp =
            QKV + (size_t)(b * 2048 + qbase + w * 16 + la) * 3072 + h * 64;
        bf16x8 qf0 = *(const bf16x8*)(qp + lg * 8);
        bf16x8 qf1 = *(const bf16x8*)(qp + 32 + lg * 8);

        f32x4 o[4];
#pragma unroll
        for (int n = 0; n < 4; n++) o[n] = (f32x4){0.f, 0.f, 0.f, 0.f};
        float mrow[4] = {-1e30f, -1e30f, -1e30f, -1e30f};
        float lrow[4] = {0.f, 0.f, 0.f, 0.f};

        const int nt = qt + 1;
        for (int kt = 0; kt < nt; ++kt) {
            const int kv = kt * 64;
            __syncthreads();
            gload16(kg + (size_t)(kv + srow) * 3072 + sxcol, Ks + t * 8);
            gload16(kg + (size_t)(kv + 32 + srow) * 3072 + sxcol, Ks + 2048 + t * 8);
            gload16(vg + (size_t)srow * 2048 + kv + sxcol, Vs + t * 8);
            gload16(vg + (size_t)(32 + srow) * 2048 + kv + sxcol, Vs + 2048 + t * 8);
            __syncthreads();

            // S[16q][64k] = Q @ K^T  (swizzled Ks reads: conflict-free)
            f32x4 sa[4];
#pragma unroll
            for (int n = 0; n < 4; n++) {
                f32x4 z = (f32x4){0.f, 0.f, 0.f, 0.f};
                const unsigned short* kr = Ks + (n * 16 + la) * 64;
                bf16x8 k0 = *(const bf16x8*)(kr + (lg ^ xk) * 8);
                bf16x8 k1 = *(const bf16x8*)(kr + ((4 | lg) ^ xk) * 8);
                z = __builtin_amdgcn_mfma_f32_16x16x32_bf16(qf0, k0, z, 0, 0, 0);
                z = __builtin_amdgcn_mfma_f32_16x16x32_bf16(qf1, k1, z, 0, 0, 0);
                sa[n] = z;
            }
            const bool diag = (kt == nt - 1);
#pragma unroll
            for (int n = 0; n < 4; n++)
#pragma unroll
                for (int j = 0; j < 4; j++) {
                    float s = sa[n][j] * 0.125f;  // 1/sqrt(64)
                    if (diag) {
                        int qr = qbase + w * 16 + lg * 4 + j;
                        int kc = kv + n * 16 + la;
                        if (kc > qr) s = -1e30f;
                    }
                    sa[n][j] = s;
                }
            float pm[4];
#pragma unroll
            for (int j = 0; j < 4; j++)
                pm[j] = fmaxf(fmaxf(sa[0][j], sa[1][j]), fmaxf(sa[2][j], sa[3][j]));
#pragma unroll
            for (int off = 1; off < 16; off <<= 1)
#pragma unroll
                for (int j = 0; j < 4; j++)
                    pm[j] = fmaxf(pm[j], __shfl_xor(pm[j], off, 64));
            float alpha[4];
#pragma unroll
            for (int j = 0; j < 4; j++) {
                float mn = fmaxf(mrow[j], pm[j]);
                alpha[j] = exp2f((mrow[j] - mn) * 1.44269504f);
                mrow[j] = mn;
            }
            float psum[4] = {0.f, 0.f, 0.f, 0.f};
#pragma unroll
            for (int n = 0; n < 4; n++)
#pragma unroll
                for (int j = 0; j < 4; j++) {
                    float pr = exp2f((sa[n][j] - mrow[j]) * 1.44269504f);
                    sa[n][j] = pr;
                    psum[j] += pr;
                }
#pragma unroll
            for (int off = 1; off < 16; off <<= 1)
#pragma unroll
                for (int j = 0; j < 4; j++)
                    psum[j] += __shfl_xor(psum[j], off, 64);
#pragma unroll
            for (int j = 0; j < 4; j++) {
                lrow[j] = lrow[j] * alpha[j] + psum[j];
                o[0][j] *= alpha[j]; o[1][j] *= alpha[j];
                o[2][j] *= alpha[j]; o[3][j] *= alpha[j];
            }
            // P (C-layout) -> per-wave LDS (swizzled write/read)
#pragma unroll
            for (int n = 0; n < 4; n++)
#pragma unroll
                for (int j = 0; j < 4; j++) {
                    int qr = lg * 4 + j;
                    int col = n * 16 + la;
                    pw[qr * 64 + (((col >> 3) ^ (qr & 7)) * 8) + (col & 7)] =
                        f2bf(sa[n][j]);
                }
            asm volatile("s_waitcnt lgkmcnt(0)" ::: "memory");
#pragma unroll
            for (int kk = 0; kk < 2; kk++) {
                bf16x8 pa = *(const bf16x8*)(pw + la * 64 + (((kk * 4 + lg) ^ xk) * 8));
#pragma unroll
                for (int n = 0; n < 4; n++) {
                    bf16x8 vb = *(const bf16x8*)(
                        Vs + (n * 16 + la) * 64 + (((kk * 4 + lg) ^ xk) * 8));
                    o[n] = __builtin_amdgcn_mfma_f32_16x16x32_bf16(pa, vb, o[n], 0, 0, 0);
                }
            }
        }
        float inv[4];
#pragma unroll
        for (int j = 0; j < 4; j++) inv[j] = 1.0f / lrow[j];
#pragma unroll
        for (int n = 0; n < 4; n++)
#pragma unroll
            for (int j = 0; j < 4; j++) {
                int row = b * 2048 + qbase + w * 16 + lg * 4 + j;
                int col = h * 64 + n * 16 + la;
                ctx[(size_t)row * 1024 + col] = f2bf(o[n][j] * inv[j]);
            }
    }
}

// ---------------------------------------------------------------------------
// LayerNorm (unbiased var, ddof=1), D=1024, one block per row, f32 -> bf16
// ---------------------------------------------------------------------------
__global__ __launch_bounds__(256) void ln_kernel(
    const float* __restrict__ x, const float* __restrict__ scale,
    const float* __restrict__ shift, unsigned short* __restrict__ out)
{
    const int row = blockIdx.x, t = threadIdx.x;
    const int lane = t & 63, w = t >> 6;
    const float4 v = ((const float4*)(x + (size_t)row * 1024))[t];
    float s = v.x + v.y + v.z + v.w;
#pragma unroll
    for (int off = 1; off < 64; off <<= 1) s += __shfl_xor(s, off, 64);
    __shared__ float red[8];
    if (lane == 0) red[w] = s;
    __syncthreads();
    float mean = (red[0] + red[1] + red[2] + red[3]) * (1.0f / 1024.0f);
    float d0 = v.x - mean, d1 = v.y - mean, d2 = v.z - mean, d3 = v.w - mean;
    float q = d0 * d0 + d1 * d1 + d2 * d2 + d3 * d3;
#pragma unroll
    for (int off = 1; off < 64; off <<= 1) q += __shfl_xor(q, off, 64);
    if (lane == 0) red[4 + w] = q;
    __syncthreads();
    float var = (red[4] + red[5] + red[6] + red[7]) * (1.0f / 1023.0f);
    float rinv = rsqrtf(var + 1e-6f);
    const int c = t * 4;
    out[(size_t)row * 1024 + c + 0] = f2bf(scale[c + 0] * (d0 * rinv) + shift[c + 0]);
    out[(size_t)row * 1024 + c + 1] = f2bf(scale[c + 1] * (d1 * rinv) + shift[c + 1]);
    out[(size_t)row * 1024 + c + 2] = f2bf(scale[c + 2] * (d2 * rinv) + shift[c + 2]);
    out[(size_t)row * 1024 + c + 3] = f2bf(scale[c + 3] * (d3 * rinv) + shift[c + 3]);
}

// ---------------------------------------------------------------------------
// Weight transpose: W[K][N] f32 -> Wt[N][K] bf16. block(32,8), grid(N/32,K/32)
// ---------------------------------------------------------------------------
__global__ __launch_bounds__(256) void transpose_w(
    const float* __restrict__ W, unsigned short* __restrict__ Wt, int K, int N)
{
    __shared__ float tile[32][33];
    const int nb = blockIdx.x * 32, kb = blockIdx.y * 32;
    const int tx = threadIdx.x, ty = threadIdx.y;
#pragma unroll
    for (int j = 0; j < 4; j++)
        tile[ty + j * 8][tx] = W[(size_t)(kb + ty + j * 8) * N + nb + tx];
    __syncthreads();
#pragma unroll
    for (int j = 0; j < 4; j++)
        Wt[(size_t)(nb + ty + j * 8) * K + kb + tx] = f2bf(tile[tx][ty + j * 8]);
}

// ---------------------------------------------------------------------------
// V transpose: QKV V-section [s][h*64+hd] -> Vt[b][h][hd][s]
// block(32,8), grid(S/32, 2, B*H)
// ---------------------------------------------------------------------------
__global__ __launch_bounds__(256) void transpose_v(
    const unsigned short* __restrict__ QKV, unsigned short* __restrict__ Vt)
{
    __shared__ unsigned short tile[32][33];
    const int sb = blockIdx.x * 32, hb = blockIdx.y * 32;
    const int bh = blockIdx.z;
    const int b = bh >> 4, h = bh & 15;
    const int tx = threadIdx.x, ty = threadIdx.y;
    const unsigned short* src = QKV + (size_t)(b * 2048) * 3072 + 2048 + h * 64;
#pragma unroll
    for (int j = 0; j < 4; j++)
        tile[ty + j * 8][tx] = src[(size_t)(sb + ty + j * 8) * 3072 + hb + tx];
    __syncthreads();
    unsigned short* dst = Vt + (size_t)((b * 16 + h) * 64) * 2048;
#pragma unroll
    for (int j = 0; j < 4; j++)
        dst[(size_t)(hb + ty + j * 8) * 2048 + sb + tx] = tile[tx][ty + j * 8];
}

// ---------------------------------------------------------------------------
extern "C" void kernel_launch(void* const* d_in, const int* in_sizes, int n_in,
                              void* d_out, int out_size, void* d_ws, size_t ws_size,
                              hipStream_t stream)
{
    const float* x      = (const float*)d_in[0];
    const float* Wq     = (const float*)d_in[1];
    const float* Wk     = (const float*)d_in[2];
    const float* Wv     = (const float*)d_in[3];
    const float* Wo     = (const float*)d_in[4];
    const float* bo     = (const float*)d_in[5];
    const float* W1     = (const float*)d_in[6];
    const float* b1     = (const float*)d_in[7];
    const float* W2     = (const float*)d_in[8];
    const float* b2     = (const float*)d_in[9];
    const float* scale1 = (const float*)d_in[10];
    const float* shift1 = (const float*)d_in[11];
    const float* scale2 = (const float*)d_in[12];
    const float* shift2 = (const float*)d_in[13];
    float* out = (float*)d_out;

    char* ws = (char*)d_ws;
    unsigned short* xn    = (unsigned short*)(ws);                   // 8MB (also yn)
    unsigned short* QKV   = (unsigned short*)(ws + (8ull << 20));    // 24MB
    unsigned short* VtB   = (unsigned short*)(ws + (32ull << 20));   // 8MB
    unsigned short* ctx   = (unsigned short*)(ws + (40ull << 20));   // 8MB
    unsigned short* g     = (unsigned short*)(ws + (8ull << 20));    // 32MB (reuse QKV+Vt)
    unsigned short* WqkvT = (unsigned short*)(ws + (48ull << 20));   // 6MB
    unsigned short* WoT   = (unsigned short*)(ws + (54ull << 20));   // 2MB
    unsigned short* W1T   = (unsigned short*)(ws + (56ull << 20));   // 8MB
    unsigned short* W2T   = (unsigned short*)(ws + (64ull << 20));   // 8MB -> 72MB total
    float* h = out;  // h lives in d_out

    dim3 blk(256);
    dim3 tb(32, 8);

    transpose_w<<<dim3(32, 32), tb, 0, stream>>>(Wq, WqkvT, 1024, 1024);
    transpose_w<<<dim3(32, 32), tb, 0, stream>>>(Wk, WqkvT + 1024 * 1024, 1024, 1024);
    transpose_w<<<dim3(32, 32), tb, 0, stream>>>(Wv, WqkvT + 2 * 1024 * 1024, 1024, 1024);
    transpose_w<<<dim3(32, 32), tb, 0, stream>>>(Wo, WoT, 1024, 1024);
    transpose_w<<<dim3(128, 32), tb, 0, stream>>>(W1, W1T, 1024, 4096);
    transpose_w<<<dim3(32, 128), tb, 0, stream>>>(W2, W2T, 4096, 1024);

    ln_kernel<<<4096, blk, 0, stream>>>(x, scale1, shift1, xn);
    gemm_bt<0><<<dim3(32, 24), blk, 0, stream>>>(xn, WqkvT, QKV, nullptr, nullptr,
                                                 4096, 3072, 1024);
    transpose_v<<<dim3(64, 2, 32), tb, 0, stream>>>(QKV, VtB);
    // balanced causal attention: 16 pairs x 16 heads x 2 batch
    attn_kernel<<<dim3(16, 16, 2), blk, 0, stream>>>(QKV, VtB, ctx);
    gemm_bt<1><<<dim3(32, 8), blk, 0, stream>>>(ctx, WoT, h, bo, x, 4096, 1024, 1024);
    ln_kernel<<<4096, blk, 0, stream>>>(h, scale2, shift2, xn);
    gemm_bt<2><<<dim3(32, 32), blk, 0, stream>>>(xn, W1T, g, b1, nullptr, 4096, 4096, 1024);
    gemm_bt<1><<<dim3(32, 8), blk, 0, stream>>>(g, W2T, out, b2, h, 4096, 1024, 4096);
}

// Round 3
// 318.224 us; speedup vs baseline: 1.3476x; 1.0764x over previous
//
#include <hip/hip_runtime.h>
#include <hip/hip_bf16.h>

typedef __attribute__((ext_vector_type(4))) float f32x4;
typedef __attribute__((ext_vector_type(8))) short bf16x8;

#define AS1 __attribute__((address_space(1)))
#define AS3 __attribute__((address_space(3)))

__device__ __forceinline__ void gload16(const void* g, void* l) {
    __builtin_amdgcn_global_load_lds((AS1 const void*)g, (AS3 void*)l, 16, 0, 0);
}

__device__ __forceinline__ unsigned short f2bf(float f) {
    union { float f; unsigned int u; } v; v.f = f;
    unsigned int u = v.u;
    unsigned int r = (u + 0x7FFFu + ((u >> 16) & 1u)) >> 16;
    return (unsigned short)r;
}

__device__ __forceinline__ float gelu_t(float x) {
    float u = 0.7978845608028654f * (x + 0.044715f * x * x * x);
    return 0.5f * x * (1.0f + tanhf(u));
}

// ---------------------------------------------------------------------------
// Generic bf16 GEMM: C(MxN) = A(MxK) @ Bt(NxK)^T  [+ epilogue]
// EPI 0: store bf16 | EPI 1: v+bias[col]+res -> f32 | EPI 2: gelu(v+bias)->bf16
// 128x128 tile, BK=32, 256 threads (4 waves, 2x2), m97 2-barrier structure.
// Used where grid >= ~3 blocks/CU.
// ---------------------------------------------------------------------------
template<int EPI>
__global__ __launch_bounds__(256) void gemm_bt(
    const unsigned short* __restrict__ A,
    const unsigned short* __restrict__ Bt,
    void* __restrict__ C,
    const float* __restrict__ bias,
    const float* __restrict__ res,
    int M, int N, int K)
{
    __shared__ alignas(16) unsigned short As[128 * 32];
    __shared__ alignas(16) unsigned short Bs[128 * 32];
    const int t = threadIdx.x;
    const int lane = t & 63;
    const int w = t >> 6;
    const int la = lane & 15, lg = lane >> 4;
    const int brow = blockIdx.x * 128, bcol = blockIdx.y * 128;
    const int wr = (w >> 1) * 64, wc = (w & 1) * 64;

    const int srow = t >> 2;
    const int scol = (t & 3) * 8;
    const unsigned short* aS0 = A + (size_t)(brow + srow) * K + scol;
    const unsigned short* aS1 = A + (size_t)(brow + 64 + srow) * K + scol;
    const unsigned short* bS0 = Bt + (size_t)(bcol + srow) * K + scol;
    const unsigned short* bS1 = Bt + (size_t)(bcol + 64 + srow) * K + scol;
    unsigned short* aD = As + t * 8;
    unsigned short* bD = Bs + t * 8;

    f32x4 acc[4][4];
#pragma unroll
    for (int m = 0; m < 4; m++)
#pragma unroll
        for (int n = 0; n < 4; n++)
            acc[m][n] = (f32x4){0.f, 0.f, 0.f, 0.f};

    for (int k0 = 0; k0 < K; k0 += 32) {
        __syncthreads();
        gload16(aS0 + k0, aD);
        gload16(aS1 + k0, aD + 2048);
        gload16(bS0 + k0, bD);
        gload16(bS1 + k0, bD + 2048);
        __syncthreads();

        bf16x8 af[4], bfv[4];
#pragma unroll
        for (int m = 0; m < 4; m++)
            af[m] = *(const bf16x8*)(As + (wr + m * 16 + la) * 32 + lg * 8);
#pragma unroll
        for (int n = 0; n < 4; n++)
            bfv[n] = *(const bf16x8*)(Bs + (wc + n * 16 + la) * 32 + lg * 8);
#pragma unroll
        for (int m = 0; m < 4; m++)
#pragma unroll
            for (int n = 0; n < 4; n++)
                acc[m][n] = __builtin_amdgcn_mfma_f32_16x16x32_bf16(
                    af[m], bfv[n], acc[m][n], 0, 0, 0);
    }

#pragma unroll
    for (int m = 0; m < 4; m++)
#pragma unroll
        for (int n = 0; n < 4; n++)
#pragma unroll
            for (int j = 0; j < 4; j++) {
                int row = brow + wr + m * 16 + lg * 4 + j;
                int col = bcol + wc + n * 16 + la;
                float v = acc[m][n][j];
                if (EPI == 0) {
                    ((unsigned short*)C)[(size_t)row * N + col] = f2bf(v);
                } else if (EPI == 1) {
                    ((float*)C)[(size_t)row * N + col] =
                        v + bias[col] + res[(size_t)row * N + col];
                } else {
                    ((unsigned short*)C)[(size_t)row * N + col] =
                        f2bf(gelu_t(v + bias[col]));
                }
            }
}

// ---------------------------------------------------------------------------
// Split-K grouped GEMM for small grids (N=1024 -> only 256 blocks at 128x128).
// 1024 threads = 4 groups x 4 waves. Group g accumulates K-range
// [g*K/4, (g+1)*K/4) for the SAME 128x128 tile in its own LDS staging pair,
// so 16 loads/iter are in flight per CU and iterations drop 4x.
// Combine: groups 3,2,1 serially write acc to a padded LDS f32 buffer,
// group 0 adds; group 0 runs the epilogue. No extra HBM traffic, no atomics.
// ---------------------------------------------------------------------------
template<int EPI>
__global__ __launch_bounds__(1024) void gemm_bt_ks(
    const unsigned short* __restrict__ A,
    const unsigned short* __restrict__ Bt,
    void* __restrict__ C,
    const float* __restrict__ bias,
    const float* __restrict__ res,
    int M, int N, int K)
{
    // staging: 4 groups x (8KB A + 8KB B) = 64KB; combine: 128x132 f32 = 67.5KB
    __shared__ alignas(16) char smem[128 * 132 * 4];
    const int t = threadIdx.x;
    const int g = t >> 8;          // group 0..3
    const int tl = t & 255;        // thread within group
    const int lane = t & 63;
    const int w = tl >> 6;         // wave within group
    const int la = lane & 15, lg = lane >> 4;
    const int brow = blockIdx.x * 128, bcol = blockIdx.y * 128;
    const int wr = (w >> 1) * 64, wc = (w & 1) * 64;

    const int Kg = K >> 2;
    const int kbase = g * Kg;
    unsigned short* Asg = (unsigned short*)(smem + g * 16384);
    unsigned short* Bsg = Asg + 4096;

    const int srow = tl >> 2;
    const int scol = (tl & 3) * 8;
    const unsigned short* aS0 = A + (size_t)(brow + srow) * K + kbase + scol;
    const unsigned short* aS1 = A + (size_t)(brow + 64 + srow) * K + kbase + scol;
    const unsigned short* bS0 = Bt + (size_t)(bcol + srow) * K + kbase + scol;
    const unsigned short* bS1 = Bt + (size_t)(bcol + 64 + srow) * K + kbase + scol;
    unsigned short* aD = Asg + tl * 8;
    unsigned short* bD = Bsg + tl * 8;

    f32x4 acc[4][4];
#pragma unroll
    for (int m = 0; m < 4; m++)
#pragma unroll
        for (int n = 0; n < 4; n++)
            acc[m][n] = (f32x4){0.f, 0.f, 0.f, 0.f};

    for (int k0 = 0; k0 < Kg; k0 += 32) {
        __syncthreads();
        gload16(aS0 + k0, aD);
        gload16(aS1 + k0, aD + 2048);
        gload16(bS0 + k0, bD);
        gload16(bS1 + k0, bD + 2048);
        __syncthreads();

        bf16x8 af[4], bfv[4];
#pragma unroll
        for (int m = 0; m < 4; m++)
            af[m] = *(const bf16x8*)(Asg + (wr + m * 16 + la) * 32 + lg * 8);
#pragma unroll
        for (int n = 0; n < 4; n++)
            bfv[n] = *(const bf16x8*)(Bsg + (wc + n * 16 + la) * 32 + lg * 8);
#pragma unroll
        for (int m = 0; m < 4; m++)
#pragma unroll
            for (int n = 0; n < 4; n++)
                acc[m][n] = __builtin_amdgcn_mfma_f32_16x16x32_bf16(
                    af[m], bfv[n], acc[m][n], 0, 0, 0);
    }

    // serial cross-group combine through LDS (row stride 132 words: no 2^k bank alias)
    float* cbuf = (float*)smem;
    for (int s = 3; s >= 1; --s) {
        __syncthreads();
        if (g == s) {
#pragma unroll
            for (int m = 0; m < 4; m++)
#pragma unroll
                for (int n = 0; n < 4; n++)
#pragma unroll
                    for (int j = 0; j < 4; j++)
                        cbuf[(wr + m * 16 + lg * 4 + j) * 132 + wc + n * 16 + la] =
                            acc[m][n][j];
        }
        __syncthreads();
        if (g == 0) {
#pragma unroll
            for (int m = 0; m < 4; m++)
#pragma unroll
                for (int n = 0; n < 4; n++)
#pragma unroll
                    for (int j = 0; j < 4; j++)
                        acc[m][n][j] +=
                            cbuf[(wr + m * 16 + lg * 4 + j) * 132 + wc + n * 16 + la];
        }
    }
    if (g != 0) return;

#pragma unroll
    for (int m = 0; m < 4; m++)
#pragma unroll
        for (int n = 0; n < 4; n++)
#pragma unroll
            for (int j = 0; j < 4; j++) {
                int row = brow + wr + m * 16 + lg * 4 + j;
                int col = bcol + wc + n * 16 + la;
                float v = acc[m][n][j];
                if (EPI == 0) {
                    ((unsigned short*)C)[(size_t)row * N + col] = f2bf(v);
                } else if (EPI == 1) {
                    ((float*)C)[(size_t)row * N + col] =
                        v + bias[col] + res[(size_t)row * N + col];
                } else {
                    ((unsigned short*)C)[(size_t)row * N + col] =
                        f2bf(gelu_t(v + bias[col]));
                }
            }
}

// ---------------------------------------------------------------------------
// Causal flash attention, swizzled LDS + work-balanced pairing.
// ---------------------------------------------------------------------------
__global__ __launch_bounds__(256) void attn_kernel(
    const unsigned short* __restrict__ QKV,
    const unsigned short* __restrict__ Vt,
    unsigned short* __restrict__ ctx)
{
    __shared__ alignas(16) unsigned short Ks[64 * 64];
    __shared__ alignas(16) unsigned short Vs[64 * 64];
    __shared__ alignas(16) unsigned short Ps[4][16 * 64];
    const int t = threadIdx.x, lane = t & 63, w = t >> 6;
    const int la = lane & 15, lg = lane >> 4;
    const int p = blockIdx.x, h = blockIdx.y, b = blockIdx.z;

    const unsigned short* kg = QKV + (size_t)(b * 2048) * 3072 + 1024 + h * 64;
    const unsigned short* vg = Vt + (size_t)((b * 16 + h) * 64) * 2048;
    const int srow = t >> 3;
    const int sxcol = (((t & 7) ^ (srow & 7)) * 8);

    unsigned short* pw = (unsigned short*)Ps[w];
    const int xk = la & 7;

    for (int half = 0; half < 2; ++half) {
        const int qt = half ? (31 - p) : p;
        const int qbase = qt * 64;

        const unsigned short* qp =
            QKV + (size_t)(b * 2048 + qbase + w * 16 + la) * 3072 + h * 64;
        bf16x8 qf0 = *(const bf16x8*)(qp + lg * 8);
        bf16x8 qf1 = *(const bf16x8*)(qp + 32 + lg * 8);

        f32x4 o[4];
#pragma unroll
        for (int n = 0; n < 4; n++) o[n] = (f32x4){0.f, 0.f, 0.f, 0.f};
        float mrow[4] = {-1e30f, -1e30f, -1e30f, -1e30f};
        float lrow[4] = {0.f, 0.f, 0.f, 0.f};

        const int nt = qt + 1;
        for (int kt = 0; kt < nt; ++kt) {
            const int kv = kt * 64;
            __syncthreads();
            gload16(kg + (size_t)(kv + srow) * 3072 + sxcol, Ks + t * 8);
            gload16(kg + (size_t)(kv + 32 + srow) * 3072 + sxcol, Ks + 2048 + t * 8);
            gload16(vg + (size_t)srow * 2048 + kv + sxcol, Vs + t * 8);
            gload16(vg + (size_t)(32 + srow) * 2048 + kv + sxcol, Vs + 2048 + t * 8);
            __syncthreads();

            f32x4 sa[4];
#pragma unroll
            for (int n = 0; n < 4; n++) {
                f32x4 z = (f32x4){0.f, 0.f, 0.f, 0.f};
                const unsigned short* kr = Ks + (n * 16 + la) * 64;
                bf16x8 k0 = *(const bf16x8*)(kr + (lg ^ xk) * 8);
                bf16x8 k1 = *(const bf16x8*)(kr + ((4 | lg) ^ xk) * 8);
                z = __builtin_amdgcn_mfma_f32_16x16x32_bf16(qf0, k0, z, 0, 0, 0);
                z = __builtin_amdgcn_mfma_f32_16x16x32_bf16(qf1, k1, z, 0, 0, 0);
                sa[n] = z;
            }
            const bool diag = (kt == nt - 1);
#pragma unroll
            for (int n = 0; n < 4; n++)
#pragma unroll
                for (int j = 0; j < 4; j++) {
                    float s = sa[n][j] * 0.125f;
                    if (diag) {
                        int qr = qbase + w * 16 + lg * 4 + j;
                        int kc = kv + n * 16 + la;
                        if (kc > qr) s = -1e30f;
                    }
                    sa[n][j] = s;
                }
            float pm[4];
#pragma unroll
            for (int j = 0; j < 4; j++)
                pm[j] = fmaxf(fmaxf(sa[0][j], sa[1][j]), fmaxf(sa[2][j], sa[3][j]));
#pragma unroll
            for (int off = 1; off < 16; off <<= 1)
#pragma unroll
                for (int j = 0; j < 4; j++)
                    pm[j] = fmaxf(pm[j], __shfl_xor(pm[j], off, 64));
            float alpha[4];
#pragma unroll
            for (int j = 0; j < 4; j++) {
                float mn = fmaxf(mrow[j], pm[j]);
                alpha[j] = exp2f((mrow[j] - mn) * 1.44269504f);
                mrow[j] = mn;
            }
            float psum[4] = {0.f, 0.f, 0.f, 0.f};
#pragma unroll
            for (int n = 0; n < 4; n++)
#pragma unroll
                for (int j = 0; j < 4; j++) {
                    float pr = exp2f((sa[n][j] - mrow[j]) * 1.44269504f);
                    sa[n][j] = pr;
                    psum[j] += pr;
                }
#pragma unroll
            for (int off = 1; off < 16; off <<= 1)
#pragma unroll
                for (int j = 0; j < 4; j++)
                    psum[j] += __shfl_xor(psum[j], off, 64);
#pragma unroll
            for (int j = 0; j < 4; j++) {
                lrow[j] = lrow[j] * alpha[j] + psum[j];
                o[0][j] *= alpha[j]; o[1][j] *= alpha[j];
                o[2][j] *= alpha[j]; o[3][j] *= alpha[j];
            }
#pragma unroll
            for (int n = 0; n < 4; n++)
#pragma unroll
                for (int j = 0; j < 4; j++) {
                    int qr = lg * 4 + j;
                    int col = n * 16 + la;
                    pw[qr * 64 + (((col >> 3) ^ (qr & 7)) * 8) + (col & 7)] =
                        f2bf(sa[n][j]);
                }
            asm volatile("s_waitcnt lgkmcnt(0)" ::: "memory");
#pragma unroll
            for (int kk = 0; kk < 2; kk++) {
                bf16x8 pa = *(const bf16x8*)(pw + la * 64 + (((kk * 4 + lg) ^ xk) * 8));
#pragma unroll
                for (int n = 0; n < 4; n++) {
                    bf16x8 vb = *(const bf16x8*)(
                        Vs + (n * 16 + la) * 64 + (((kk * 4 + lg) ^ xk) * 8));
                    o[n] = __builtin_amdgcn_mfma_f32_16x16x32_bf16(pa, vb, o[n], 0, 0, 0);
                }
            }
        }
        float inv[4];
#pragma unroll
        for (int j = 0; j < 4; j++) inv[j] = 1.0f / lrow[j];
#pragma unroll
        for (int n = 0; n < 4; n++)
#pragma unroll
            for (int j = 0; j < 4; j++) {
                int row = b * 2048 + qbase + w * 16 + lg * 4 + j;
                int col = h * 64 + n * 16 + la;
                ctx[(size_t)row * 1024 + col] = f2bf(o[n][j] * inv[j]);
            }
    }
}

// ---------------------------------------------------------------------------
__global__ __launch_bounds__(256) void ln_kernel(
    const float* __restrict__ x, const float* __restrict__ scale,
    const float* __restrict__ shift, unsigned short* __restrict__ out)
{
    const int row = blockIdx.x, t = threadIdx.x;
    const int lane = t & 63, w = t >> 6;
    const float4 v = ((const float4*)(x + (size_t)row * 1024))[t];
    float s = v.x + v.y + v.z + v.w;
#pragma unroll
    for (int off = 1; off < 64; off <<= 1) s += __shfl_xor(s, off, 64);
    __shared__ float red[8];
    if (lane == 0) red[w] = s;
    __syncthreads();
    float mean = (red[0] + red[1] + red[2] + red[3]) * (1.0f / 1024.0f);
    float d0 = v.x - mean, d1 = v.y - mean, d2 = v.z - mean, d3 = v.w - mean;
    float q = d0 * d0 + d1 * d1 + d2 * d2 + d3 * d3;
#pragma unroll
    for (int off = 1; off < 64; off <<= 1) q += __shfl_xor(q, off, 64);
    if (lane == 0) red[4 + w] = q;
    __syncthreads();
    float var = (red[4] + red[5] + red[6] + red[7]) * (1.0f / 1023.0f);
    float rinv = rsqrtf(var + 1e-6f);
    const int c = t * 4;
    out[(size_t)row * 1024 + c + 0] = f2bf(scale[c + 0] * (d0 * rinv) + shift[c + 0]);
    out[(size_t)row * 1024 + c + 1] = f2bf(scale[c + 1] * (d1 * rinv) + shift[c + 1]);
    out[(size_t)row * 1024 + c + 2] = f2bf(scale[c + 2] * (d2 * rinv) + shift[c + 2]);
    out[(size_t)row * 1024 + c + 3] = f2bf(scale[c + 3] * (d3 * rinv) + shift[c + 3]);
}

// ---------------------------------------------------------------------------
__global__ __launch_bounds__(256) void transpose_w(
    const float* __restrict__ W, unsigned short* __restrict__ Wt, int K, int N)
{
    __shared__ float tile[32][33];
    const int nb = blockIdx.x * 32, kb = blockIdx.y * 32;
    const int tx = threadIdx.x, ty = threadIdx.y;
#pragma unroll
    for (int j = 0; j < 4; j++)
        tile[ty + j * 8][tx] = W[(size_t)(kb + ty + j * 8) * N + nb + tx];
    __syncthreads();
#pragma unroll
    for (int j = 0; j < 4; j++)
        Wt[(size_t)(nb + ty + j * 8) * K + kb + tx] = f2bf(tile[tx][ty + j * 8]);
}

// ---------------------------------------------------------------------------
__global__ __launch_bounds__(256) void transpose_v(
    const unsigned short* __restrict__ QKV, unsigned short* __restrict__ Vt)
{
    __shared__ unsigned short tile[32][33];
    const int sb = blockIdx.x * 32, hb = blockIdx.y * 32;
    const int bh = blockIdx.z;
    const int b = bh >> 4, h = bh & 15;
    const int tx = threadIdx.x, ty = threadIdx.y;
    const unsigned short* src = QKV + (size_t)(b * 2048) * 3072 + 2048 + h * 64;
#pragma unroll
    for (int j = 0; j < 4; j++)
        tile[ty + j * 8][tx] = src[(size_t)(sb + ty + j * 8) * 3072 + hb + tx];
    __syncthreads();
    unsigned short* dst = Vt + (size_t)((b * 16 + h) * 64) * 2048;
#pragma unroll
    for (int j = 0; j < 4; j++)
        dst[(size_t)(hb + ty + j * 8) * 2048 + sb + tx] = tile[tx][ty + j * 8];
}

// ---------------------------------------------------------------------------
extern "C" void kernel_launch(void* const* d_in, const int* in_sizes, int n_in,
                              void* d_out, int out_size, void* d_ws, size_t ws_size,
                              hipStream_t stream)
{
    const float* x      = (const float*)d_in[0];
    const float* Wq     = (const float*)d_in[1];
    const float* Wk     = (const float*)d_in[2];
    const float* Wv     = (const float*)d_in[3];
    const float* Wo     = (const float*)d_in[4];
    const float* bo     = (const float*)d_in[5];
    const float* W1     = (const float*)d_in[6];
    const float* b1     = (const float*)d_in[7];
    const float* W2     = (const float*)d_in[8];
    const float* b2     = (const float*)d_in[9];
    const float* scale1 = (const float*)d_in[10];
    const float* shift1 = (const float*)d_in[11];
    const float* scale2 = (const float*)d_in[12];
    const float* shift2 = (const float*)d_in[13];
    float* out = (float*)d_out;

    char* ws = (char*)d_ws;
    unsigned short* xn    = (unsigned short*)(ws);                   // 8MB (also yn)
    unsigned short* QKV   = (unsigned short*)(ws + (8ull << 20));    // 24MB
    unsigned short* VtB   = (unsigned short*)(ws + (32ull << 20));   // 8MB
    unsigned short* ctx   = (unsigned short*)(ws + (40ull << 20));   // 8MB
    unsigned short* g     = (unsigned short*)(ws + (8ull << 20));    // 32MB (reuse QKV+Vt)
    unsigned short* WqkvT = (unsigned short*)(ws + (48ull << 20));   // 6MB
    unsigned short* WoT   = (unsigned short*)(ws + (54ull << 20));   // 2MB
    unsigned short* W1T   = (unsigned short*)(ws + (56ull << 20));   // 8MB
    unsigned short* W2T   = (unsigned short*)(ws + (64ull << 20));   // 8MB -> 72MB total
    float* h = out;  // h lives in d_out

    dim3 blk(256);
    dim3 tb(32, 8);

    transpose_w<<<dim3(32, 32), tb, 0, stream>>>(Wq, WqkvT, 1024, 1024);
    transpose_w<<<dim3(32, 32), tb, 0, stream>>>(Wk, WqkvT + 1024 * 1024, 1024, 1024);
    transpose_w<<<dim3(32, 32), tb, 0, stream>>>(Wv, WqkvT + 2 * 1024 * 1024, 1024, 1024);
    transpose_w<<<dim3(32, 32), tb, 0, stream>>>(Wo, WoT, 1024, 1024);
    transpose_w<<<dim3(128, 32), tb, 0, stream>>>(W1, W1T, 1024, 4096);
    transpose_w<<<dim3(32, 128), tb, 0, stream>>>(W2, W2T, 4096, 1024);

    ln_kernel<<<4096, blk, 0, stream>>>(x, scale1, shift1, xn);
    gemm_bt<0><<<dim3(32, 24), blk, 0, stream>>>(xn, WqkvT, QKV, nullptr, nullptr,
                                                 4096, 3072, 1024);
    transpose_v<<<dim3(64, 2, 32), tb, 0, stream>>>(QKV, VtB);
    attn_kernel<<<dim3(16, 16, 2), blk, 0, stream>>>(QKV, VtB, ctx);
    // h = x + ctx @ Wo + bo  (split-K grouped: 256 blocks x 1024 threads)
    gemm_bt_ks<1><<<dim3(32, 8), dim3(1024), 0, stream>>>(ctx, WoT, h, bo, x,
                                                          4096, 1024, 1024);
    ln_kernel<<<4096, blk, 0, stream>>>(h, scale2, shift2, xn);
    gemm_bt<2><<<dim3(32, 32), blk, 0, stream>>>(xn, W1T, g, b1, nullptr, 4096, 4096, 1024);
    // out = h + g @ W2 + b2  (split-K grouped)
    gemm_bt_ks<1><<<dim3(32, 8), dim3(1024), 0, stream>>>(g, W2T, out, b2, h,
                                                          4096, 1024, 4096);
}